// Round 4
// baseline (28.268 us; speedup 1.0000x reference)
//
#include <hip/hip_runtime.h>
#include <hip/hip_bf16.h>
#include <math.h>

#define LOG2E 1.4426950408889634f
#define LN2   0.6931471805599453f

typedef float v2f __attribute__((ext_vector_type(2)));

__device__ __forceinline__ float fast_exp2(float x) {
#if __has_builtin(__builtin_amdgcn_exp2f)
    return __builtin_amdgcn_exp2f(x);
#else
    return exp2f(x);
#endif
}

// ---------------------------------------------------------------------------
// Single fused kernel, coefficients-in-registers structure.
// Block = 256 threads (4 waves) handles 64 samples; each WAVE handles 16
// samples against ALL M=1024 components.
//  Phase 1: redundant per-block coefficient prep (log2 domain, Lmax anchor):
//           t_ij = c0 + c1 x + c2 y + d0 x^2 + d1 xy + d2 y^2  (<= 0)
//  Phase 2: each lane loads 16 components (8 packed pairs, 96 VGPRs) from LDS.
//  Phase 3: per sample (wave-uniform s_load of x,y): 40 v_pk_fma + 16 v_exp,
//           then 6-step shfl_xor cross-lane sum. Zero LDS/VMEM streaming.
// ---------------------------------------------------------------------------
__global__ __launch_bounds__(256) void gm_fused(
        const float* __restrict__ sample,   // [N,2]
        const float* __restrict__ mu,       // [M,2]
        const float* __restrict__ A,        // [M,2,2]
        const float* __restrict__ w,        // [M,1]
        float* __restrict__ out) {          // [N,1]
    __shared__ float COEF[1024 * 6];        // [comp][6] = c0,c1,c2,d0,d1,d2
    __shared__ float RED4[4];

    const int tid  = threadIdx.x;
    const int lane = tid & 63;
    const int wid  = tid >> 6;

    // ================= Phase 1: coefficient prep (per block) ==============
    const float4 wv = ((const float4*)w)[tid];     // comps 4t..4t+3

    float v = fmaxf(fmaxf(wv.x, wv.y), fmaxf(wv.z, wv.w));
    #pragma unroll
    for (int o = 32; o; o >>= 1) v = fmaxf(v, __shfl_xor(v, o));
    if (lane == 0) RED4[wid] = v;
    __syncthreads();
    const float wmax = fmaxf(fmaxf(RED4[0], RED4[1]), fmaxf(RED4[2], RED4[3]));
    __syncthreads();

    v = expf(wv.x - wmax) + expf(wv.y - wmax) + expf(wv.z - wmax) + expf(wv.w - wmax);
    #pragma unroll
    for (int o = 32; o; o >>= 1) v += __shfl_xor(v, o);
    if (lane == 0) RED4[wid] = v;
    __syncthreads();
    const float lse = wmax + logf(RED4[0] + RED4[1] + RED4[2] + RED4[3]);
    __syncthreads();                               // RED4 reused below

    const float wj[4] = {wv.x, wv.y, wv.z, wv.w};
    float lw2[4], G00[4], G2[4], G11[4], MXa[4], MYa[4];
    #pragma unroll
    for (int k = 0; k < 4; k++) {
        const int j = 4 * tid + k;
        const float4 a = ((const float4*)A)[j];
        const float g00 = 0.5f * (a.x*a.x + a.y*a.y);
        const float g01 = 0.5f * (a.x*a.z + a.y*a.w);
        const float g11 = 0.5f * (a.z*a.z + a.w*a.w);
        const float det = g00*g11 - g01*g01;
        lw2[k] = ((wj[k] - lse) + 0.5f * logf(det)) * LOG2E;
        G00[k] = g00 * LOG2E;
        G2[k]  = 2.f * g01 * LOG2E;
        G11[k] = g11 * LOG2E;
        const float2 m = ((const float2*)mu)[j];
        MXa[k] = m.x; MYa[k] = m.y;
    }

    v = fmaxf(fmaxf(lw2[0], lw2[1]), fmaxf(lw2[2], lw2[3]));
    #pragma unroll
    for (int o = 32; o; o >>= 1) v = fmaxf(v, __shfl_xor(v, o));
    if (lane == 0) RED4[wid] = v;
    __syncthreads();
    const float Lmax = fmaxf(fmaxf(RED4[0], RED4[1]), fmaxf(RED4[2], RED4[3]));

    #pragma unroll
    for (int k = 0; k < 4; k++) {
        const int j = 4 * tid + k;
        const float mx = MXa[k], my = MYa[k];
        const float c1 = 2.f*G00[k]*mx + G2[k]*my;
        const float c2 = G2[k]*mx + 2.f*G11[k]*my;
        const float c0 = lw2[k] - (G00[k]*mx*mx + G2[k]*mx*my + G11[k]*my*my) - Lmax;
        float* p = &COEF[j * 6];
        p[0] = c0;      p[1] = c1;     p[2] = c2;
        p[3] = -G00[k]; p[4] = -G2[k]; p[5] = -G11[k];
    }
    __syncthreads();

    // ========= Phase 2: 16 comps/lane -> 8 packed pairs in VGPRs ==========
    // pair k of lane l: components (l + 128k, l + 128k + 64)
    v2f C0[8], C1[8], C2[8], D0[8], D1[8], D2[8];
    #pragma unroll
    for (int k = 0; k < 8; k++) {
        const float* pa = &COEF[(lane + 128*k) * 6];
        const float* pb = &COEF[(lane + 128*k + 64) * 6];
        C0[k] = (v2f){pa[0], pb[0]};
        C1[k] = (v2f){pa[1], pb[1]};
        C2[k] = (v2f){pa[2], pb[2]};
        D0[k] = (v2f){pa[3], pb[3]};
        D1[k] = (v2f){pa[4], pb[4]};
        D2[k] = (v2f){pa[5], pb[5]};
    }

    // ================= Phase 3: hot loop over 16 samples ===================
    const int sbase = blockIdx.x * 64 + wid * 16;
    const int ubase = __builtin_amdgcn_readfirstlane(sbase);
    float myout = 0.f;

    for (int s = 0; s < 16; ++s) {
        const float2 xy = ((const float2*)sample)[ubase + s];   // uniform s_load
        const float x = xy.x, y = xy.y;
        const v2f Xv = {x, x}, Yv = {y, y};

        v2f sv = {0.f, 0.f};
        #pragma unroll
        for (int k = 0; k < 8; k++) {
            // t = c0 + x*(c1 + d0*x + d1*y) + y*(c2 + d2*y)
            v2f i1 = __builtin_elementwise_fma(D0[k], Xv, C1[k]);
            i1     = __builtin_elementwise_fma(D1[k], Yv, i1);
            v2f i2 = __builtin_elementwise_fma(D2[k], Yv, C2[k]);
            v2f t  = __builtin_elementwise_fma(i1, Xv, C0[k]);
            t      = __builtin_elementwise_fma(i2, Yv, t);
            sv.x += fast_exp2(t.x);
            sv.y += fast_exp2(t.y);
        }
        float st = sv.x + sv.y;
        #pragma unroll
        for (int o = 32; o; o >>= 1) st += __shfl_xor(st, o);   // uniform result

        float ll;
        if (st >= 1e-30f) {
            ll = LN2 * (Lmax + log2f(st));
        } else {
            // Rare underflow: re-anchored two-pass over this lane's 16 comps
            // + cross-lane max/sum (wave-uniform branch, taken ~never).
            float m = -3e38f;
            #pragma unroll
            for (int k = 0; k < 8; k++) {
                v2f i1 = __builtin_elementwise_fma(D0[k], Xv, C1[k]);
                i1     = __builtin_elementwise_fma(D1[k], Yv, i1);
                v2f i2 = __builtin_elementwise_fma(D2[k], Yv, C2[k]);
                v2f t  = __builtin_elementwise_fma(i1, Xv, C0[k]);
                t      = __builtin_elementwise_fma(i2, Yv, t);
                m = fmaxf(m, fmaxf(t.x, t.y));
            }
            #pragma unroll
            for (int o = 32; o; o >>= 1) m = fmaxf(m, __shfl_xor(m, o));
            float ss = 0.f;
            #pragma unroll
            for (int k = 0; k < 8; k++) {
                v2f i1 = __builtin_elementwise_fma(D0[k], Xv, C1[k]);
                i1     = __builtin_elementwise_fma(D1[k], Yv, i1);
                v2f i2 = __builtin_elementwise_fma(D2[k], Yv, C2[k]);
                v2f t  = __builtin_elementwise_fma(i1, Xv, C0[k]);
                t      = __builtin_elementwise_fma(i2, Yv, t);
                ss += fast_exp2(t.x - m) + fast_exp2(t.y - m);
            }
            #pragma unroll
            for (int o = 32; o; o >>= 1) ss += __shfl_xor(ss, o);
            ll = LN2 * (Lmax + m + log2f(ss));
        }
        if (lane == s) myout = ll;      // lane s keeps sample s's result
    }
    if (lane < 16) out[sbase + lane] = myout;
}

extern "C" void kernel_launch(void* const* d_in, const int* in_sizes, int n_in,
                              void* d_out, int out_size, void* d_ws, size_t ws_size,
                              hipStream_t stream) {
    const float* sample = (const float*)d_in[0];   // [N,2]
    const float* mu     = (const float*)d_in[1];   // [M,2]
    const float* A      = (const float*)d_in[2];   // [M,2,2]
    const float* w      = (const float*)d_in[3];   // [M,1]
    float* out = (float*)d_out;

    const int N = in_sizes[0] / 2;                 // 65536
    // M fixed at 1024 (register/LDS layout sized statically).

    gm_fused<<<N / 64, 256, 0, stream>>>(sample, mu, A, w, out);
}

// Round 5
// 23.080 us; speedup vs baseline: 1.2248x; 1.2248x over previous
//
#include <hip/hip_runtime.h>
#include <hip/hip_bf16.h>
#include <math.h>

#define LOG2E 1.4426950408889634f
#define LN2   0.6931471805599453f

typedef float v2f __attribute__((ext_vector_type(2)));

__device__ __forceinline__ float fast_exp2(float x) {
#if __has_builtin(__builtin_amdgcn_exp2f)
    return __builtin_amdgcn_exp2f(x);
#else
    return exp2f(x);
#endif
}

// ---------------------------------------------------------------------------
// Prep kernel: one block of M=1024 threads. Coefficients in log2 domain,
// anchored at Lmax so t_ij = c0 + c1 x + c2 y + d0 x^2 + d1 xy + d2 y^2 <= 0.
// Output layout: gcoef[c][j], c in {c0,c1,c2,d0,d1,d2}, j = component.
// ---------------------------------------------------------------------------
__global__ __launch_bounds__(1024) void gm_prep(
        const float* __restrict__ mu,   // [M,2]
        const float* __restrict__ A,    // [M,2,2]
        const float* __restrict__ w,    // [M,1]
        float* __restrict__ gcoef,      // [6][1024]
        float* __restrict__ outLmax) {
    __shared__ float red[16];
    const int j = threadIdx.x;
    const float wj = w[j];

    // block max of w
    float v = wj;
    #pragma unroll
    for (int o = 32; o; o >>= 1) v = fmaxf(v, __shfl_xor(v, o));
    if ((j & 63) == 0) red[j >> 6] = v;
    __syncthreads();
    float wmax = red[0];
    #pragma unroll
    for (int k = 1; k < 16; k++) wmax = fmaxf(wmax, red[k]);
    __syncthreads();

    // block sum of exp(w - wmax)
    v = expf(wj - wmax);
    #pragma unroll
    for (int o = 32; o; o >>= 1) v += __shfl_xor(v, o);
    if ((j & 63) == 0) red[j >> 6] = v;
    __syncthreads();
    float sumew = 0.f;
    #pragma unroll
    for (int k = 0; k < 16; k++) sumew += red[k];
    __syncthreads();
    const float lse = wmax + logf(sumew);

    // gamma = A A^T / 2, log-weight (log2 domain)
    const float a00 = A[4*j + 0], a01 = A[4*j + 1];
    const float a10 = A[4*j + 2], a11 = A[4*j + 3];
    const float g00 = 0.5f * (a00*a00 + a01*a01);
    const float g01 = 0.5f * (a00*a10 + a01*a11);
    const float g11 = 0.5f * (a10*a10 + a11*a11);
    const float det = g00*g11 - g01*g01;
    const float lw2 = ((wj - lse) + 0.5f * logf(det)) * LOG2E;

    // Lmax = max_j lw2_j
    v = lw2;
    #pragma unroll
    for (int o = 32; o; o >>= 1) v = fmaxf(v, __shfl_xor(v, o));
    if ((j & 63) == 0) red[j >> 6] = v;
    __syncthreads();
    float Lmax = red[0];
    #pragma unroll
    for (int k = 1; k < 16; k++) Lmax = fmaxf(Lmax, red[k]);

    const float G00 = g00 * LOG2E;
    const float G2  = 2.f * g01 * LOG2E;
    const float G11 = g11 * LOG2E;
    const float mx = mu[2*j + 0], my = mu[2*j + 1];
    gcoef[0*1024 + j] = lw2 - (G00*mx*mx + G2*mx*my + G11*my*my) - Lmax; // c0
    gcoef[1*1024 + j] = 2.f*G00*mx + G2*my;                              // c1
    gcoef[2*1024 + j] = G2*mx + 2.f*G11*my;                              // c2
    gcoef[3*1024 + j] = -G00;                                            // d0
    gcoef[4*1024 + j] = -G2;                                             // d1
    gcoef[5*1024 + j] = -G11;                                            // d2
    if (j == 0) outLmax[0] = Lmax;
}

// ---------------------------------------------------------------------------
// Main kernel: block = 256 thr (4 waves) handles 32 samples.
//   wave w: group = w>>1 owns samples [group*16,group*16+16);
//           half  = w&1  owns components [half*512, half*512+512).
//   Each lane privately holds 8 components (4 packed pairs) in VGPRs,
//   loaded coalesced from global (L2-hot, 24 KB shared by all blocks).
//   Samples are wave-uniform (s_load). Per-lane per-sample partial sums
//   go to LDS once; a two-stage transpose reduce finishes each sample.
// ---------------------------------------------------------------------------
__global__ __launch_bounds__(256) void gm_main(
        const float* __restrict__ sample,   // [N,2]
        const float* __restrict__ gcoef,    // [6][1024]
        const float* __restrict__ gLmax,
        float* __restrict__ out) {          // [N,1]
    __shared__ float RED[2][16][130];       // [group][s][l2], padded row
    __shared__ float PART[32][9];

    const int tid   = threadIdx.x;
    const int lane  = tid & 63;
    const int wid   = __builtin_amdgcn_readfirstlane(tid >> 6);
    const int group = wid >> 1;
    const int half  = wid & 1;

    // ---- preload this lane's 4 component-pairs into VGPRs ----
    v2f C0[4], C1[4], C2[4], D0[4], D1[4], D2[4];
    #pragma unroll
    for (int k = 0; k < 4; k++) {
        const int j = half*512 + 128*k + lane;   // pair (j, j+64)
        C0[k] = (v2f){gcoef[0*1024 + j], gcoef[0*1024 + j + 64]};
        C1[k] = (v2f){gcoef[1*1024 + j], gcoef[1*1024 + j + 64]};
        C2[k] = (v2f){gcoef[2*1024 + j], gcoef[2*1024 + j + 64]};
        D0[k] = (v2f){gcoef[3*1024 + j], gcoef[3*1024 + j + 64]};
        D1[k] = (v2f){gcoef[4*1024 + j], gcoef[4*1024 + j + 64]};
        D2[k] = (v2f){gcoef[5*1024 + j], gcoef[5*1024 + j + 64]};
    }

    const int sbase = blockIdx.x * 32 + group * 16;

    // ---- hot loop: 16 wave-uniform samples ----
    #pragma unroll
    for (int s = 0; s < 16; ++s) {
        const float2 xy = ((const float2*)sample)[sbase + s];  // uniform s_load
        const v2f Xv = {xy.x, xy.x}, Yv = {xy.y, xy.y};

        v2f sv = {0.f, 0.f};
        #pragma unroll
        for (int k = 0; k < 4; k++) {
            // t = c0 + x*(c1 + d0*x + d1*y) + y*(c2 + d2*y)
            v2f i1 = __builtin_elementwise_fma(D0[k], Xv, C1[k]);
            i1     = __builtin_elementwise_fma(D1[k], Yv, i1);
            v2f i2 = __builtin_elementwise_fma(D2[k], Yv, C2[k]);
            v2f t  = __builtin_elementwise_fma(i1, Xv, C0[k]);
            t      = __builtin_elementwise_fma(i2, Yv, t);
            sv.x += fast_exp2(t.x);
            sv.y += fast_exp2(t.y);
        }
        RED[group][s][half*64 + lane] = sv.x + sv.y;
    }
    __syncthreads();

    // ---- stage 1: 8 partials per sample ----
    {
        const int r  = tid >> 3;          // 0..31 = local sample
        const int c8 = tid & 7;
        const float* row = &RED[r >> 4][r & 15][c8 * 16];
        float p = 0.f;
        #pragma unroll
        for (int i = 0; i < 16; i++) p += row[i];
        PART[r][c8] = p;
    }
    __syncthreads();

    // ---- stage 2: finish 32 samples ----
    if (tid < 32) {
        float st = 0.f;
        #pragma unroll
        for (int c = 0; c < 8; c++) st += PART[tid][c];
        const float Lmax = gLmax[0];
        const int si = blockIdx.x * 32 + tid;
        float ll;
        if (st >= 1e-30f) {
            ll = LN2 * (Lmax + log2f(st));
        } else {
            // Rare underflow: re-anchored two-pass over all M from global.
            const float2 xy = ((const float2*)sample)[si];
            const float x = xy.x, y = xy.y;
            float m = -3e38f;
            for (int j = 0; j < 1024; j++) {
                float i1 = fmaf(gcoef[3*1024+j], x, gcoef[1*1024+j]);
                i1 = fmaf(gcoef[4*1024+j], y, i1);
                float i2 = fmaf(gcoef[5*1024+j], y, gcoef[2*1024+j]);
                float t = fmaf(i1, x, gcoef[0*1024+j]);
                t = fmaf(i2, y, t);
                m = fmaxf(m, t);
            }
            float ss = 0.f;
            for (int j = 0; j < 1024; j++) {
                float i1 = fmaf(gcoef[3*1024+j], x, gcoef[1*1024+j]);
                i1 = fmaf(gcoef[4*1024+j], y, i1);
                float i2 = fmaf(gcoef[5*1024+j], y, gcoef[2*1024+j]);
                float t = fmaf(i1, x, gcoef[0*1024+j]);
                t = fmaf(i2, y, t);
                ss += fast_exp2(t - m);
            }
            ll = LN2 * (Lmax + m + log2f(ss));
        }
        out[si] = ll;
    }
}

extern "C" void kernel_launch(void* const* d_in, const int* in_sizes, int n_in,
                              void* d_out, int out_size, void* d_ws, size_t ws_size,
                              hipStream_t stream) {
    const float* sample = (const float*)d_in[0];   // [N,2]
    const float* mu     = (const float*)d_in[1];   // [M,2]
    const float* A      = (const float*)d_in[2];   // [M,2,2]
    const float* w      = (const float*)d_in[3];   // [M,1]
    float* out = (float*)d_out;

    const int N = in_sizes[0] / 2;                 // 65536
    // M fixed at 1024 (layouts sized statically).

    float* gcoef = (float*)d_ws;                   // 6*1024*4 = 24576 B
    float* lmax  = (float*)((char*)d_ws + 24576);  // 4 B

    gm_prep<<<1, 1024, 0, stream>>>(mu, A, w, gcoef, lmax);
    gm_main<<<N / 32, 256, 0, stream>>>(sample, gcoef, lmax, out);
}

// Round 6
// 19.583 us; speedup vs baseline: 1.4435x; 1.1786x over previous
//
#include <hip/hip_runtime.h>
#include <math.h>

#define LOG2E 1.4426950408889634f
#define LN2   0.6931471805599453f

typedef float v2f __attribute__((ext_vector_type(2)));

__device__ __forceinline__ float fast_exp2(float x) {
#if __has_builtin(__builtin_amdgcn_exp2f)
    return __builtin_amdgcn_exp2f(x);
#else
    return exp2f(x);
#endif
}

// ---------------------------------------------------------------------------
// Single fused kernel, register-resident coefficients.
// Block = 512 threads (8 waves), handles 128 samples. 2 blocks/CU.
//  Phase 1: redundant per-block prep (2 comps/thread), log2 domain, Lmax
//           anchor:  t_ij = c0 + c1 x + c2 y + d0 x^2 + d1 xy + d2 y^2 <= 0.
//           COEF layout [6][1024] so phase-2 reads are conflict-free.
//  Phase 2: each lane privately loads 16 comps = 8 packed pairs (96 VGPRs).
//  Phase 3: each wave sweeps its 16 samples (wave-uniform s_load): per
//           sample 40 v_pk_fma + 16 v_exp + 16 v_add, ONE ds_write_b32.
//           No cross-lane ops, no LDS broadcast streams in the hot loop.
//  Reduce: two-stage LDS transpose reduce, one log2 per sample.
// ---------------------------------------------------------------------------
__global__ __launch_bounds__(512, 4) void gm_fused(
        const float* __restrict__ sample,   // [N,2]
        const float* __restrict__ mu,       // [M,2]
        const float* __restrict__ A,        // [M,2,2]
        const float* __restrict__ w,        // [M,1]
        float* __restrict__ out) {          // [N,1]
    __shared__ float COEF[6][1024];         // 24 KB
    __shared__ float RED[128][65];          // 33.3 KB, padded
    __shared__ float PART[128][5];          // 2.6 KB, padded
    __shared__ float red8[8];

    const int tid  = threadIdx.x;
    const int lane = tid & 63;
    const int wid  = tid >> 6;              // 0..7

    // ================= Phase 1: coefficient prep ==========================
    const float2 wv = ((const float2*)w)[tid];      // comps 2t, 2t+1

    float v = fmaxf(wv.x, wv.y);
    #pragma unroll
    for (int o = 32; o; o >>= 1) v = fmaxf(v, __shfl_xor(v, o));
    if (lane == 0) red8[wid] = v;
    __syncthreads();
    float wmax = red8[0];
    #pragma unroll
    for (int k = 1; k < 8; k++) wmax = fmaxf(wmax, red8[k]);
    __syncthreads();

    v = expf(wv.x - wmax) + expf(wv.y - wmax);
    #pragma unroll
    for (int o = 32; o; o >>= 1) v += __shfl_xor(v, o);
    if (lane == 0) red8[wid] = v;
    __syncthreads();
    float sumew = 0.f;
    #pragma unroll
    for (int k = 0; k < 8; k++) sumew += red8[k];
    const float lse = wmax + logf(sumew);
    __syncthreads();                                 // red8 reused below

    float lw2[2], G00[2], G2[2], G11[2], MX[2], MY[2];
    const float wj[2] = {wv.x, wv.y};
    #pragma unroll
    for (int k = 0; k < 2; k++) {
        const int j = 2 * tid + k;
        const float4 a = ((const float4*)A)[j];
        const float g00 = 0.5f * (a.x*a.x + a.y*a.y);
        const float g01 = 0.5f * (a.x*a.z + a.y*a.w);
        const float g11 = 0.5f * (a.z*a.z + a.w*a.w);
        const float det = g00*g11 - g01*g01;
        lw2[k] = ((wj[k] - lse) + 0.5f * logf(det)) * LOG2E;
        G00[k] = g00 * LOG2E;
        G2[k]  = 2.f * g01 * LOG2E;
        G11[k] = g11 * LOG2E;
        const float2 m = ((const float2*)mu)[j];
        MX[k] = m.x; MY[k] = m.y;
    }

    v = fmaxf(lw2[0], lw2[1]);
    #pragma unroll
    for (int o = 32; o; o >>= 1) v = fmaxf(v, __shfl_xor(v, o));
    if (lane == 0) red8[wid] = v;
    __syncthreads();
    float Lmax = red8[0];
    #pragma unroll
    for (int k = 1; k < 8; k++) Lmax = fmaxf(Lmax, red8[k]);

    #pragma unroll
    for (int k = 0; k < 2; k++) {
        const int j = 2 * tid + k;
        const float mx = MX[k], my = MY[k];
        COEF[0][j] = lw2[k] - (G00[k]*mx*mx + G2[k]*mx*my + G11[k]*my*my) - Lmax;
        COEF[1][j] = 2.f*G00[k]*mx + G2[k]*my;
        COEF[2][j] = G2[k]*mx + 2.f*G11[k]*my;
        COEF[3][j] = -G00[k];
        COEF[4][j] = -G2[k];
        COEF[5][j] = -G11[k];
    }
    __syncthreads();

    // ========= Phase 2: 16 comps/lane -> 8 packed pairs in VGPRs ==========
    v2f C0[8], C1[8], C2[8], D0[8], D1[8], D2[8];
    #pragma unroll
    for (int k = 0; k < 8; k++) {
        const int j = 128*k + lane;              // pair (j, j+64)
        C0[k] = (v2f){COEF[0][j], COEF[0][j+64]};
        C1[k] = (v2f){COEF[1][j], COEF[1][j+64]};
        C2[k] = (v2f){COEF[2][j], COEF[2][j+64]};
        D0[k] = (v2f){COEF[3][j], COEF[3][j+64]};
        D1[k] = (v2f){COEF[4][j], COEF[4][j+64]};
        D2[k] = (v2f){COEF[5][j], COEF[5][j+64]};
    }

    // ================= Phase 3: hot loop, 16 uniform samples ==============
    const int ls0 = wid * 16;                                  // local base
    const int sbu = __builtin_amdgcn_readfirstlane(blockIdx.x * 128 + ls0);

    for (int s = 0; s < 16; ++s) {
        const float2 xy = ((const float2*)sample)[sbu + s];    // s_load
        const v2f Xv = {xy.x, xy.x}, Yv = {xy.y, xy.y};

        v2f sv = {0.f, 0.f};
        #pragma unroll
        for (int k = 0; k < 8; k++) {
            // t = c0 + x*(c1 + d0*x + d1*y) + y*(c2 + d2*y)
            v2f i1 = __builtin_elementwise_fma(D0[k], Xv, C1[k]);
            i1     = __builtin_elementwise_fma(D1[k], Yv, i1);
            v2f i2 = __builtin_elementwise_fma(D2[k], Yv, C2[k]);
            v2f t  = __builtin_elementwise_fma(i1, Xv, C0[k]);
            t      = __builtin_elementwise_fma(i2, Yv, t);
            sv.x += fast_exp2(t.x);
            sv.y += fast_exp2(t.y);
        }
        RED[ls0 + s][lane] = sv.x + sv.y;
    }
    __syncthreads();

    // ---- stage 1: 4 partials per sample (2-way LDS access, free) ----
    {
        const int r = tid >> 2, c = tid & 3;
        const float* row = &RED[r][c * 16];
        float p = 0.f;
        #pragma unroll
        for (int i = 0; i < 16; i++) p += row[i];
        PART[r][c] = p;
    }
    __syncthreads();

    // ---- stage 2: finish 128 samples ----
    if (tid < 128) {
        const float st = (PART[tid][0] + PART[tid][1])
                       + (PART[tid][2] + PART[tid][3]);
        const int si = blockIdx.x * 128 + tid;
        float ll;
        if (st >= 1e-30f) {
            ll = LN2 * (Lmax + log2f(st));
        } else {
            // Rare underflow: re-anchored two-pass over all M from LDS COEF.
            const float2 xy = ((const float2*)sample)[si];
            const float x = xy.x, y = xy.y;
            float m = -3e38f;
            for (int j = 0; j < 1024; j++) {
                float i1 = fmaf(COEF[3][j], x, COEF[1][j]);
                i1 = fmaf(COEF[4][j], y, i1);
                float i2 = fmaf(COEF[5][j], y, COEF[2][j]);
                float t = fmaf(i1, x, COEF[0][j]);
                t = fmaf(i2, y, t);
                m = fmaxf(m, t);
            }
            float ss = 0.f;
            for (int j = 0; j < 1024; j++) {
                float i1 = fmaf(COEF[3][j], x, COEF[1][j]);
                i1 = fmaf(COEF[4][j], y, i1);
                float i2 = fmaf(COEF[5][j], y, COEF[2][j]);
                float t = fmaf(i1, x, COEF[0][j]);
                t = fmaf(i2, y, t);
                ss += fast_exp2(t - m);
            }
            ll = LN2 * (Lmax + m + log2f(ss));
        }
        out[si] = ll;
    }
}

extern "C" void kernel_launch(void* const* d_in, const int* in_sizes, int n_in,
                              void* d_out, int out_size, void* d_ws, size_t ws_size,
                              hipStream_t stream) {
    const float* sample = (const float*)d_in[0];   // [N,2]
    const float* mu     = (const float*)d_in[1];   // [M,2]
    const float* A      = (const float*)d_in[2];   // [M,2,2]
    const float* w      = (const float*)d_in[3];   // [M,1]
    float* out = (float*)d_out;

    const int N = in_sizes[0] / 2;                 // 65536
    // M fixed at 1024 (register/LDS layouts sized statically).

    gm_fused<<<N / 128, 512, 0, stream>>>(sample, mu, A, w, out);
}